// Round 1
// baseline (287.530 us; speedup 1.0000x reference)
//
#include <hip/hip_runtime.h>
#include <hip/hip_bf16.h>
#include <math.h>

#define NN 100000
#define DD 384
#define HH 128
#define KK 5
#define KT 128

constexpr float INIT_VAL = 1.4142135623730951e-3f; // 1/sqrt(N*K)
constexpr float RSQRT5   = 0.44721359549995793f;   // 1/sqrt(5)

// ---------------- fold qv @ W1[384:768] into bias ----------------
__global__ void fold_bias_kernel(const float* __restrict__ qv, const float* __restrict__ W1,
                                 const float* __restrict__ b1, float* __restrict__ b1p) {
    int h = threadIdx.x;  // 128 threads
    float s = b1[h];
    for (int k = 0; k < DD; ++k) s = fmaf(qv[k], W1[(DD + k) * HH + h], s);
    b1p[h] = s;
}

// ---------------- transpose nbr to SoA + fill init state ----------------
__global__ void prep_walk_kernel(const int* __restrict__ nbr, int* __restrict__ nbrT,
                                 float* __restrict__ u0) {
    int i = blockIdx.x * blockDim.x + threadIdx.x;
    if (i >= NN) return;
#pragma unroll
    for (int j = 0; j < KK; ++j) {
        nbrT[j * NN + i] = nbr[i * KK + j];
        u0[j * NN + i] = INIT_VAL;
    }
}

// ---------------- fused MLP -> g = a/||a|| (or 1/sqrt(5) fallback) ----------------
// block: 256 threads = 32 h-groups (4 hidden each) x 8 node-groups (8 nodes each)
// block tile: 64 nodes x 128 hidden, K staged in LDS tiles of 128
__global__ __launch_bounds__(256) void mlp_kernel(
    const float* __restrict__ emb, const float* __restrict__ W1,
    const float* __restrict__ b1p, const float* __restrict__ W2,
    const float* __restrict__ b2, float* __restrict__ gout /* [KK][NN] */) {
    __shared__ __align__(16) float es[64][KT];  // 32 KB
    const int tid = threadIdx.x;
    const int hg = tid & 31;
    const int ng = tid >> 5;  // 0..7
    const int h0 = hg * 4;
    const int nodeBase = blockIdx.x * 64;

    float acc[8][4];
#pragma unroll
    for (int r = 0; r < 8; ++r) {
        acc[r][0] = 0.f; acc[r][1] = 0.f; acc[r][2] = 0.f; acc[r][3] = 0.f;
    }

    for (int t = 0; t < DD / KT; ++t) {
        const int k0 = t * KT;
        __syncthreads();
#pragma unroll
        for (int i = 0; i < 8; ++i) {  // 64 rows x 32 float4 = 2048 / 256 threads
            int idx = tid + i * 256;
            int r = idx >> 5;
            int c = idx & 31;
            int node = nodeBase + r;
            float4 v = make_float4(0.f, 0.f, 0.f, 0.f);
            if (node < NN) v = *reinterpret_cast<const float4*>(&emb[(size_t)node * DD + k0 + c * 4]);
            *reinterpret_cast<float4*>(&es[r][c * 4]) = v;
        }
        __syncthreads();
        for (int c = 0; c < KT; c += 4) {
            float4 w0  = *reinterpret_cast<const float4*>(&W1[(k0 + c + 0) * HH + h0]);
            float4 w1  = *reinterpret_cast<const float4*>(&W1[(k0 + c + 1) * HH + h0]);
            float4 w2v = *reinterpret_cast<const float4*>(&W1[(k0 + c + 2) * HH + h0]);
            float4 w3  = *reinterpret_cast<const float4*>(&W1[(k0 + c + 3) * HH + h0]);
#pragma unroll
            for (int r = 0; r < 8; ++r) {
                float4 e = *reinterpret_cast<const float4*>(&es[ng * 8 + r][c]);
                acc[r][0] = fmaf(e.x, w0.x, acc[r][0]);
                acc[r][0] = fmaf(e.y, w1.x, acc[r][0]);
                acc[r][0] = fmaf(e.z, w2v.x, acc[r][0]);
                acc[r][0] = fmaf(e.w, w3.x, acc[r][0]);
                acc[r][1] = fmaf(e.x, w0.y, acc[r][1]);
                acc[r][1] = fmaf(e.y, w1.y, acc[r][1]);
                acc[r][1] = fmaf(e.z, w2v.y, acc[r][1]);
                acc[r][1] = fmaf(e.w, w3.y, acc[r][1]);
                acc[r][2] = fmaf(e.x, w0.z, acc[r][2]);
                acc[r][2] = fmaf(e.y, w1.z, acc[r][2]);
                acc[r][2] = fmaf(e.z, w2v.z, acc[r][2]);
                acc[r][2] = fmaf(e.w, w3.z, acc[r][2]);
                acc[r][3] = fmaf(e.x, w0.w, acc[r][3]);
                acc[r][3] = fmaf(e.y, w1.w, acc[r][3]);
                acc[r][3] = fmaf(e.z, w2v.w, acc[r][3]);
                acc[r][3] = fmaf(e.w, w3.w, acc[r][3]);
            }
        }
    }

    // epilogue: bias+relu, x W2, reduce across 32 h-groups, build g
    float b1v[4], w2r[4][KK];
#pragma unroll
    for (int i2 = 0; i2 < 4; ++i2) {
        b1v[i2] = b1p[h0 + i2];
#pragma unroll
        for (int j = 0; j < KK; ++j) w2r[i2][j] = W2[(h0 + i2) * KK + j];
    }
    float b2v[KK];
#pragma unroll
    for (int j = 0; j < KK; ++j) b2v[j] = b2[j];

#pragma unroll
    for (int r = 0; r < 8; ++r) {
        float p[KK] = {0.f, 0.f, 0.f, 0.f, 0.f};
#pragma unroll
        for (int i2 = 0; i2 < 4; ++i2) {
            float v = fmaxf(acc[r][i2] + b1v[i2], 0.f);
#pragma unroll
            for (int j = 0; j < KK; ++j) p[j] = fmaf(v, w2r[i2][j], p[j]);
        }
#pragma unroll
        for (int off = 1; off < 32; off <<= 1) {
#pragma unroll
            for (int j = 0; j < KK; ++j) p[j] += __shfl_xor(p[j], off, 32);
        }
        float a[KK];
        float an2 = 0.f;
#pragma unroll
        for (int j = 0; j < KK; ++j) {
            a[j] = p[j] + b2v[j];
            an2 = fmaf(a[j], a[j], an2);
        }
        float an = sqrtf(an2);
        bool valid = (an > 0.f) && isfinite(an) && (an2 > 0.f);
        int node = nodeBase + ng * 8 + r;
        if (hg < KK && node < NN) {
            gout[hg * NN + node] = valid ? (a[hg] / an) : RSQRT5;
        }
    }
}

// ---------------- one walk step: s_p = g (g.u); scatter-add to neighbor slots ----------------
__global__ void walk_step_kernel(const float* __restrict__ g, const int* __restrict__ nbrT,
                                 const float* __restrict__ u, float* __restrict__ v) {
    int i = blockIdx.x * blockDim.x + threadIdx.x;
    if (i >= NN) return;
    float gj[KK];
    float d = 0.f;
#pragma unroll
    for (int j = 0; j < KK; ++j) {
        gj[j] = g[j * NN + i];
        d = fmaf(gj[j], u[j * NN + i], d);
    }
#pragma unroll
    for (int j = 0; j < KK; ++j) {
        atomicAdd(&v[j * NN + nbrT[j * NN + i]], gj[j] * d);
    }
}

// ---------------- global sum of squares ----------------
__global__ void norm_reduce_kernel(const float* __restrict__ u, float* __restrict__ ss) {
    int i = blockIdx.x * blockDim.x + threadIdx.x;
    const int total = KK * NN;
    float s = 0.f;
    for (int idx = i; idx < total; idx += gridDim.x * blockDim.x) {
        float x = u[idx];
        s = fmaf(x, x, s);
    }
#pragma unroll
    for (int off = 32; off > 0; off >>= 1) s += __shfl_xor(s, off, 64);
    if ((threadIdx.x & 63) == 0) atomicAdd(ss, s);
}

// ---------------- out[i] = sum_j |u[j][i]| / ||u|| ----------------
__global__ void finalize_kernel(const float* __restrict__ u, const float* __restrict__ ss,
                                float* __restrict__ out) {
    int i = blockIdx.x * blockDim.x + threadIdx.x;
    if (i >= NN) return;
    float s = 0.f;
#pragma unroll
    for (int j = 0; j < KK; ++j) s += fabsf(u[j * NN + i]);
    float nrm = sqrtf(*ss);
    out[i] = (nrm > 0.f) ? (s / nrm) : (KK * INIT_VAL);
}

extern "C" void kernel_launch(void* const* d_in, const int* in_sizes, int n_in,
                              void* d_out, int out_size, void* d_ws, size_t ws_size,
                              hipStream_t stream) {
    const float* emb = (const float*)d_in[0];
    const float* qv  = (const float*)d_in[1];
    const float* W1  = (const float*)d_in[2];
    const float* b1  = (const float*)d_in[3];
    const float* W2  = (const float*)d_in[4];
    const float* b2  = (const float*)d_in[5];
    const int*   nbr = (const int*)d_in[6];
    float* out = (float*)d_out;

    char* ws = (char*)d_ws;
    size_t off = 0;
    auto alloc = [&](size_t bytes) {
        char* p = ws + off;
        off += (bytes + 255) & ~(size_t)255;
        return p;
    };
    float* b1p  = (float*)alloc(HH * sizeof(float));
    float* gbuf = (float*)alloc((size_t)KK * NN * sizeof(float));
    int*   nbrT = (int*)  alloc((size_t)KK * NN * sizeof(int));
    float* uA   = (float*)alloc((size_t)KK * NN * sizeof(float));
    float* uB   = (float*)alloc((size_t)KK * NN * sizeof(float));
    float* ssp  = (float*)alloc(sizeof(float));

    const size_t stateBytes = (size_t)KK * NN * sizeof(float);
    const int nblk = (NN + 255) / 256;

    fold_bias_kernel<<<1, HH, 0, stream>>>(qv, W1, b1, b1p);
    prep_walk_kernel<<<nblk, 256, 0, stream>>>(nbr, nbrT, uA);
    mlp_kernel<<<(NN + 63) / 64, 256, 0, stream>>>(emb, W1, b1p, W2, b2, gbuf);

    hipMemsetAsync(uB, 0, stateBytes, stream);
    walk_step_kernel<<<nblk, 256, 0, stream>>>(gbuf, nbrT, uA, uB);
    hipMemsetAsync(uA, 0, stateBytes, stream);
    walk_step_kernel<<<nblk, 256, 0, stream>>>(gbuf, nbrT, uB, uA);
    hipMemsetAsync(uB, 0, stateBytes, stream);
    walk_step_kernel<<<nblk, 256, 0, stream>>>(gbuf, nbrT, uA, uB);

    hipMemsetAsync(ssp, 0, sizeof(float), stream);
    norm_reduce_kernel<<<512, 256, 0, stream>>>(uB, ssp);
    finalize_kernel<<<nblk, 256, 0, stream>>>(uB, ssp, out);
}

// Round 2
// 203.269 us; speedup vs baseline: 1.4145x; 1.4145x over previous
//
#include <hip/hip_runtime.h>
#include <hip/hip_bf16.h>
#include <math.h>

#define NN 100000
#define DD 384
#define HH 128
#define KK 5

typedef __attribute__((ext_vector_type(8))) short short8;
typedef __attribute__((ext_vector_type(4))) float f32x4;

constexpr float INIT_VAL = 1.4142135623730951e-3f; // 1/sqrt(N*K)
constexpr float RSQRT5   = 0.44721359549995793f;   // 1/sqrt(5)

// split f32 -> bf16 hi + bf16 lo (truncation; |x - hi - lo| <= 2^-16 |x|)
__device__ __forceinline__ void split_bf16(float x, ushort& hi, ushort& lo) {
    unsigned xb = __float_as_uint(x);
    hi = (ushort)(xb >> 16);
    float hif = __uint_as_float(((unsigned)hi) << 16);
    lo = (ushort)(__float_as_uint(x - hif) >> 16);
}

// ---------------- fused prep ----------------
// block 0: fold qv @ W1[384:768] into bias
// blocks 1..24: pack W1[0:384] into MFMA B-fragment layout, bf16 hi/lo
//   W1frag[((c*12 + ks)*64 + lane)*8 + e] = W1[ks*32 + (lane>>4)*8 + e][c*16 + (lane&15)]
// blocks 25..415: transpose nbr to SoA
__global__ __launch_bounds__(256) void prep_kernel(
    const float* __restrict__ qv, const float* __restrict__ W1,
    const float* __restrict__ b1, const int* __restrict__ nbr,
    float* __restrict__ b1p, ushort* __restrict__ W1h, ushort* __restrict__ W1l,
    int* __restrict__ nbrT) {
    const int b = blockIdx.x, tid = threadIdx.x;
    if (b == 0) {
        if (tid < HH) {
            float s = b1[tid];
#pragma unroll 8
            for (int k = 0; k < DD; ++k)
                s = fmaf(qv[k], W1[(size_t)(DD + k) * HH + tid], s);
            b1p[tid] = s;
        }
    } else if (b <= 24) {
        int t = (b - 1) * 256 + tid;       // t = (c*12 + ks)*64 + lane, t < 6144
        int l = t & 63;
        int ks = (t >> 6) % 12;
        int c = (t >> 6) / 12;
        int k0 = ks * 32 + ((l >> 4) << 3);
        int col = c * 16 + (l & 15);
#pragma unroll
        for (int e = 0; e < 8; ++e) {
            ushort hv, lv;
            split_bf16(W1[(size_t)(k0 + e) * HH + col], hv, lv);
            W1h[(size_t)t * 8 + e] = hv;
            W1l[(size_t)t * 8 + e] = lv;
        }
    } else {
        int i = (b - 25) * 256 + tid;
        if (i < NN) {
#pragma unroll
            for (int j = 0; j < KK; ++j) nbrT[j * NN + i] = nbr[i * KK + j];
        }
    }
}

// ---------------- MFMA MLP: C = emb x W1 (hi/lo split), relu, x W2, normalize -> g ----------------
// block: 256 thr = 4 waves in 2x2; tile 64 nodes x 128 hidden; K tiled by 128.
// A staged in LDS row-major [64][128] bf16 hi/lo with XOR swizzle byte ^= (row&7)<<4.
__global__ __launch_bounds__(256) void mlp_mfma_kernel(
    const float* __restrict__ emb, const ushort* __restrict__ W1h,
    const ushort* __restrict__ W1l, const float* __restrict__ b1p,
    const float* __restrict__ W2, const float* __restrict__ b2,
    float* __restrict__ gout /* [KK][NN] */) {
    __shared__ __align__(16) ushort Ah[64 * 128];  // 16 KB
    __shared__ __align__(16) ushort Al[64 * 128];  // 16 KB
    __shared__ float pbuf[64][2][8];               // 4 KB

    const int tid = threadIdx.x;
    const int lane = tid & 63;
    const int wid = tid >> 6;
    const int wm = wid >> 1;   // 0..1: M half (32 rows)
    const int wn = wid & 1;    // 0..1: N half (64 cols)
    const int nodeBase = blockIdx.x * 64;

    f32x4 acc[2][4];
#pragma unroll
    for (int mt = 0; mt < 2; ++mt)
#pragma unroll
        for (int nt = 0; nt < 4; ++nt) acc[mt][nt] = (f32x4){0.f, 0.f, 0.f, 0.f};

    for (int t = 0; t < 3; ++t) {
        const int kbase = t * 128;
        __syncthreads();
        // stage 64 x 128 f32 -> bf16 hi/lo into swizzled LDS
#pragma unroll
        for (int i = 0; i < 8; ++i) {
            int idx = tid + i * 256;        // 0..2047
            int r = idx >> 5;               // row 0..63
            int c = idx & 31;               // float4 col 0..31
            int node = nodeBase + r;
            float4 v = make_float4(0.f, 0.f, 0.f, 0.f);
            if (node < NN)
                v = *reinterpret_cast<const float4*>(&emb[(size_t)node * DD + kbase + c * 4]);
            ushort4 hv, lv;
            split_bf16(v.x, hv.x, lv.x);
            split_bf16(v.y, hv.y, lv.y);
            split_bf16(v.z, hv.z, lv.z);
            split_bf16(v.w, hv.w, lv.w);
            int byte = (r * 256 + c * 8) ^ ((r & 7) << 4);
            *reinterpret_cast<ushort4*>(reinterpret_cast<char*>(Ah) + byte) = hv;
            *reinterpret_cast<ushort4*>(reinterpret_cast<char*>(Al) + byte) = lv;
        }
        __syncthreads();
#pragma unroll
        for (int kt = 0; kt < 4; ++kt) {
            short8 ahf[2], alf[2], bhf[4], blf[4];
#pragma unroll
            for (int mt = 0; mt < 2; ++mt) {
                int row = wm * 32 + mt * 16 + (lane & 15);
                int byte = (row * 256 + kt * 64 + ((lane >> 4) << 4)) ^ ((row & 7) << 4);
                ahf[mt] = *reinterpret_cast<const short8*>(reinterpret_cast<const char*>(Ah) + byte);
                alf[mt] = *reinterpret_cast<const short8*>(reinterpret_cast<const char*>(Al) + byte);
            }
            int ks = t * 4 + kt;
#pragma unroll
            for (int nt = 0; nt < 4; ++nt) {
                size_t off = ((size_t)((wn * 4 + nt) * 12 + ks) * 64 + lane) * 8;
                bhf[nt] = *reinterpret_cast<const short8*>(&W1h[off]);
                blf[nt] = *reinterpret_cast<const short8*>(&W1l[off]);
            }
#pragma unroll
            for (int mt = 0; mt < 2; ++mt)
#pragma unroll
                for (int nt = 0; nt < 4; ++nt) {
                    acc[mt][nt] = __builtin_amdgcn_mfma_f32_16x16x32_bf16(ahf[mt], bhf[nt], acc[mt][nt], 0, 0, 0);
                    acc[mt][nt] = __builtin_amdgcn_mfma_f32_16x16x32_bf16(alf[mt], bhf[nt], acc[mt][nt], 0, 0, 0);
                    acc[mt][nt] = __builtin_amdgcn_mfma_f32_16x16x32_bf16(ahf[mt], blf[nt], acc[mt][nt], 0, 0, 0);
                }
        }
    }

    // epilogue: v = relu(h + b1p); p[j] = sum_h v * W2[h][j]; reduce over 16 lanes
    float b1v[4], w2v[4][KK];
#pragma unroll
    for (int nt = 0; nt < 4; ++nt) {
        int h = wn * 64 + nt * 16 + (lane & 15);
        b1v[nt] = b1p[h];
#pragma unroll
        for (int j = 0; j < KK; ++j) w2v[nt][j] = W2[h * KK + j];
    }
#pragma unroll
    for (int mt = 0; mt < 2; ++mt) {
        float p[4][KK];
#pragma unroll
        for (int r = 0; r < 4; ++r)
#pragma unroll
            for (int j = 0; j < KK; ++j) p[r][j] = 0.f;
#pragma unroll
        for (int nt = 0; nt < 4; ++nt)
#pragma unroll
            for (int r = 0; r < 4; ++r) {
                float v = fmaxf(acc[mt][nt][r] + b1v[nt], 0.f);
#pragma unroll
                for (int j = 0; j < KK; ++j) p[r][j] = fmaf(v, w2v[nt][j], p[r][j]);
            }
#pragma unroll
        for (int off = 1; off < 16; off <<= 1)
#pragma unroll
            for (int r = 0; r < 4; ++r)
#pragma unroll
                for (int j = 0; j < KK; ++j) p[r][j] += __shfl_xor(p[r][j], off, 64);
        if ((lane & 15) == 0) {
            int rowbase = wm * 32 + mt * 16 + (lane >> 4) * 4;
#pragma unroll
            for (int r = 0; r < 4; ++r)
#pragma unroll
                for (int j = 0; j < KK; ++j) pbuf[rowbase + r][wn][j] = p[r][j];
        }
    }
    __syncthreads();
    if (tid < 64) {
        int node = nodeBase + tid;
        float a[KK], an2 = 0.f;
#pragma unroll
        for (int j = 0; j < KK; ++j) {
            a[j] = pbuf[tid][0][j] + pbuf[tid][1][j] + b2[j];
            an2 = fmaf(a[j], a[j], an2);
        }
        float an = sqrtf(an2);
        bool valid = (an2 > 0.f) && isfinite(an);
        if (node < NN) {
#pragma unroll
            for (int j = 0; j < KK; ++j)
                gout[j * NN + node] = valid ? (a[j] / an) : RSQRT5;
        }
    }
}

// ---------------- walk step 1: state is uniform INIT_VAL, no read ----------------
__global__ void walk_step_first(const float* __restrict__ g, const int* __restrict__ nbrT,
                                float* __restrict__ v) {
    int i = blockIdx.x * blockDim.x + threadIdx.x;
    if (i >= NN) return;
    float gj[KK], s = 0.f;
#pragma unroll
    for (int j = 0; j < KK; ++j) {
        gj[j] = g[j * NN + i];
        s += gj[j];
    }
    float d = s * INIT_VAL;
#pragma unroll
    for (int j = 0; j < KK; ++j)
        atomicAdd(&v[j * NN + nbrT[j * NN + i]], gj[j] * d);
}

// ---------------- walk step: s_p = g (g.u); scatter-add ----------------
__global__ void walk_step_kernel(const float* __restrict__ g, const int* __restrict__ nbrT,
                                 const float* __restrict__ u, float* __restrict__ v) {
    int i = blockIdx.x * blockDim.x + threadIdx.x;
    if (i >= NN) return;
    float gj[KK], d = 0.f;
#pragma unroll
    for (int j = 0; j < KK; ++j) {
        gj[j] = g[j * NN + i];
        d = fmaf(gj[j], u[j * NN + i], d);
    }
#pragma unroll
    for (int j = 0; j < KK; ++j)
        atomicAdd(&v[j * NN + nbrT[j * NN + i]], gj[j] * d);
}

// ---------------- global sum of squares (float4) ----------------
__global__ void norm_reduce_kernel(const float* __restrict__ u, float* __restrict__ ss) {
    int i = blockIdx.x * blockDim.x + threadIdx.x;
    const int total4 = (KK * NN) / 4;  // 125000
    float s = 0.f;
    for (int idx = i; idx < total4; idx += gridDim.x * blockDim.x) {
        float4 x = reinterpret_cast<const float4*>(u)[idx];
        s = fmaf(x.x, x.x, s);
        s = fmaf(x.y, x.y, s);
        s = fmaf(x.z, x.z, s);
        s = fmaf(x.w, x.w, s);
    }
#pragma unroll
    for (int off = 32; off > 0; off >>= 1) s += __shfl_xor(s, off, 64);
    if ((threadIdx.x & 63) == 0) atomicAdd(ss, s);
}

// ---------------- out[i] = sum_j |u[j][i]| / ||u|| ----------------
__global__ void finalize_kernel(const float* __restrict__ u, const float* __restrict__ ss,
                                float* __restrict__ out) {
    int i = blockIdx.x * blockDim.x + threadIdx.x;
    if (i >= NN) return;
    float s = 0.f;
#pragma unroll
    for (int j = 0; j < KK; ++j) s += fabsf(u[j * NN + i]);
    float nrm = sqrtf(*ss);
    out[i] = (nrm > 0.f) ? (s / nrm) : (KK * INIT_VAL);
}

extern "C" void kernel_launch(void* const* d_in, const int* in_sizes, int n_in,
                              void* d_out, int out_size, void* d_ws, size_t ws_size,
                              hipStream_t stream) {
    const float* emb = (const float*)d_in[0];
    const float* qv  = (const float*)d_in[1];
    const float* W1  = (const float*)d_in[2];
    const float* b1  = (const float*)d_in[3];
    const float* W2  = (const float*)d_in[4];
    const float* b2  = (const float*)d_in[5];
    const int*   nbr = (const int*)d_in[6];
    float* out = (float*)d_out;

    char* ws = (char*)d_ws;
    size_t off = 0;
    auto alloc = [&](size_t bytes) {
        char* p = ws + off;
        off += (bytes + 255) & ~(size_t)255;
        return p;
    };
    float*  b1p  = (float*)alloc(HH * sizeof(float));
    ushort* W1h  = (ushort*)alloc((size_t)DD * HH * sizeof(ushort));
    ushort* W1l  = (ushort*)alloc((size_t)DD * HH * sizeof(ushort));
    float*  gbuf = (float*)alloc((size_t)KK * NN * sizeof(float));
    int*    nbrT = (int*)  alloc((size_t)KK * NN * sizeof(int));
    float*  uA   = (float*)alloc((size_t)KK * NN * sizeof(float));
    float*  uB   = (float*)alloc((size_t)KK * NN * sizeof(float));
    float*  ssp  = (float*)alloc(sizeof(float));

    const size_t stateBytes = (size_t)KK * NN * sizeof(float);
    const int nblk = (NN + 255) / 256;

    prep_kernel<<<25 + nblk, 256, 0, stream>>>(qv, W1, b1, nbr, b1p, W1h, W1l, nbrT);
    mlp_mfma_kernel<<<(NN + 63) / 64, 256, 0, stream>>>(emb, W1h, W1l, b1p, W2, b2, gbuf);

    hipMemsetAsync(uB, 0, stateBytes, stream);
    walk_step_first<<<nblk, 256, 0, stream>>>(gbuf, nbrT, uB);
    hipMemsetAsync(uA, 0, stateBytes, stream);
    walk_step_kernel<<<nblk, 256, 0, stream>>>(gbuf, nbrT, uB, uA);
    hipMemsetAsync(uB, 0, stateBytes, stream);
    walk_step_kernel<<<nblk, 256, 0, stream>>>(gbuf, nbrT, uA, uB);

    hipMemsetAsync(ssp, 0, sizeof(float), stream);
    norm_reduce_kernel<<<512, 256, 0, stream>>>(uB, ssp);
    finalize_kernel<<<nblk, 256, 0, stream>>>(uB, ssp, out);
}

// Round 3
// 189.090 us; speedup vs baseline: 1.5206x; 1.0750x over previous
//
#include <hip/hip_runtime.h>
#include <hip/hip_bf16.h>
#include <math.h>

#define NN 100000
#define DD 384
#define HH 128
#define KK 5

typedef __attribute__((ext_vector_type(8))) short short8;
typedef __attribute__((ext_vector_type(4))) float f32x4;

constexpr float INIT_VAL = 1.4142135623730951e-3f; // 1/sqrt(N*K)
constexpr float RSQRT5   = 0.44721359549995793f;   // 1/sqrt(5)

// split f32 -> bf16 hi + bf16 lo (truncation; |x - hi - lo| <= 2^-16 |x|)
__device__ __forceinline__ void split_bf16(float x, ushort& hi, ushort& lo) {
    unsigned xb = __float_as_uint(x);
    hi = (ushort)(xb >> 16);
    float hif = __uint_as_float(((unsigned)hi) << 16);
    lo = (ushort)(__float_as_uint(x - hif) >> 16);
}

// ---------------- fused prep ----------------
// block 0: fold qv @ W1[384:768] into bias; zero ssp
// blocks 1..24: pack W1[0:384] into MFMA B-fragment layout, bf16 hi/lo
// blocks 25..: transpose nbr to SoA + zero the three scatter destination buffers
__global__ __launch_bounds__(256) void prep_kernel(
    const float* __restrict__ qv, const float* __restrict__ W1,
    const float* __restrict__ b1, const int* __restrict__ nbr,
    float* __restrict__ b1p, ushort* __restrict__ W1h, ushort* __restrict__ W1l,
    int* __restrict__ nbrT, float* __restrict__ sA, float* __restrict__ sB,
    float* __restrict__ sC, float* __restrict__ ssp) {
    const int b = blockIdx.x, tid = threadIdx.x;
    if (b == 0) {
        if (tid == 0) ssp[0] = 0.f;
        if (tid < HH) {
            float s = b1[tid];
#pragma unroll 8
            for (int k = 0; k < DD; ++k)
                s = fmaf(qv[k], W1[(size_t)(DD + k) * HH + tid], s);
            b1p[tid] = s;
        }
    } else if (b <= 24) {
        int t = (b - 1) * 256 + tid;       // t = (c*12 + ks)*64 + lane, t < 6144
        int l = t & 63;
        int ks = (t >> 6) % 12;
        int c = (t >> 6) / 12;
        int k0 = ks * 32 + ((l >> 4) << 3);
        int col = c * 16 + (l & 15);
#pragma unroll
        for (int e = 0; e < 8; ++e) {
            ushort hv, lv;
            split_bf16(W1[(size_t)(k0 + e) * HH + col], hv, lv);
            W1h[(size_t)t * 8 + e] = hv;
            W1l[(size_t)t * 8 + e] = lv;
        }
    } else {
        int i = (b - 25) * 256 + tid;
        if (i < NN) {
#pragma unroll
            for (int j = 0; j < KK; ++j) {
                nbrT[j * NN + i] = nbr[i * KK + j];
                sA[j * NN + i] = 0.f;
                sB[j * NN + i] = 0.f;
                sC[j * NN + i] = 0.f;
            }
        }
    }
}

// ---------------- MFMA MLP with software pipeline ----------------
// block: 256 thr = 4 waves (2x2); tile 64 nodes x 128 hidden; K tiled by 128.
// A staged in LDS [64][128] bf16 hi/lo, XOR swizzle byte ^= (row&7)<<4.
// Pipeline: (a) tile t+1 emb loads issued before tile-t compute (T14),
//           (b) B-frags + A-frags double-buffered one kt ahead.
__global__ __launch_bounds__(256, 2) void mlp_mfma_kernel(
    const float* __restrict__ emb, const ushort* __restrict__ W1h,
    const ushort* __restrict__ W1l, const float* __restrict__ b1p,
    const float* __restrict__ W2, const float* __restrict__ b2,
    float* __restrict__ gout /* [KK][NN] */) {
    __shared__ __align__(16) ushort Ah[64 * 128];  // 16 KB
    __shared__ __align__(16) ushort Al[64 * 128];  // 16 KB
    __shared__ float pbuf[64][2][8];               // 4 KB

    const int tid = threadIdx.x;
    const int lane = tid & 63;
    const int wid = tid >> 6;
    const int wm = wid >> 1;   // M half (32 rows)
    const int wn = wid & 1;    // N half (64 cols)
    const int nodeBase = blockIdx.x * 64;

    f32x4 acc[2][4];
#pragma unroll
    for (int mt = 0; mt < 2; ++mt)
#pragma unroll
        for (int nt = 0; nt < 4; ++nt) acc[mt][nt] = (f32x4){0.f, 0.f, 0.f, 0.f};

    // staging coords: idx = tid + i*256 -> row idx>>5, float4-col idx&31
    float4 aregs[8];
    auto issueA = [&](int t) {
#pragma unroll
        for (int i = 0; i < 8; ++i) {
            int idx = tid + i * 256;
            int r = idx >> 5, c = idx & 31;
            int node = nodeBase + r;
            aregs[i] = make_float4(0.f, 0.f, 0.f, 0.f);
            if (node < NN)
                aregs[i] = *reinterpret_cast<const float4*>(&emb[(size_t)node * DD + t * 128 + c * 4]);
        }
    };
    auto writeLDS = [&]() {
#pragma unroll
        for (int i = 0; i < 8; ++i) {
            int idx = tid + i * 256;
            int r = idx >> 5, c = idx & 31;
            ushort4 hv, lv;
            split_bf16(aregs[i].x, hv.x, lv.x);
            split_bf16(aregs[i].y, hv.y, lv.y);
            split_bf16(aregs[i].z, hv.z, lv.z);
            split_bf16(aregs[i].w, hv.w, lv.w);
            int byte = (r * 256 + c * 8) ^ ((r & 7) << 4);
            *reinterpret_cast<ushort4*>(reinterpret_cast<char*>(Ah) + byte) = hv;
            *reinterpret_cast<ushort4*>(reinterpret_cast<char*>(Al) + byte) = lv;
        }
    };

    issueA(0);
    writeLDS();
    __syncthreads();

#pragma unroll
    for (int t = 0; t < 3; ++t) {
        if (t < 2) issueA(t + 1);  // in flight across the whole compute phase

        short8 bh[2][4], bl[2][4], ah[2][2], al[2][2];
        auto loadB = [&](int kt, int s) {
            int ks = t * 4 + kt;
#pragma unroll
            for (int nt = 0; nt < 4; ++nt) {
                size_t off = ((size_t)((wn * 4 + nt) * 12 + ks) * 64 + lane) * 8;
                bh[s][nt] = *reinterpret_cast<const short8*>(&W1h[off]);
                bl[s][nt] = *reinterpret_cast<const short8*>(&W1l[off]);
            }
        };
        auto loadA = [&](int kt, int s) {
#pragma unroll
            for (int mt = 0; mt < 2; ++mt) {
                int row = wm * 32 + mt * 16 + (lane & 15);
                int byte = (row * 256 + kt * 64 + ((lane >> 4) << 4)) ^ ((row & 7) << 4);
                ah[s][mt] = *reinterpret_cast<const short8*>(reinterpret_cast<const char*>(Ah) + byte);
                al[s][mt] = *reinterpret_cast<const short8*>(reinterpret_cast<const char*>(Al) + byte);
            }
        };

        loadB(0, 0);
        loadA(0, 0);
#pragma unroll
        for (int kt = 0; kt < 4; ++kt) {
            const int cur = kt & 1, nxt = cur ^ 1;
            if (kt < 3) {
                loadB(kt + 1, nxt);
                loadA(kt + 1, nxt);
            }
#pragma unroll
            for (int mt = 0; mt < 2; ++mt)
#pragma unroll
                for (int nt = 0; nt < 4; ++nt) {
                    acc[mt][nt] = __builtin_amdgcn_mfma_f32_16x16x32_bf16(ah[cur][mt], bh[cur][nt], acc[mt][nt], 0, 0, 0);
                    acc[mt][nt] = __builtin_amdgcn_mfma_f32_16x16x32_bf16(al[cur][mt], bh[cur][nt], acc[mt][nt], 0, 0, 0);
                    acc[mt][nt] = __builtin_amdgcn_mfma_f32_16x16x32_bf16(ah[cur][mt], bl[cur][nt], acc[mt][nt], 0, 0, 0);
                }
        }

        if (t < 2) {
            __syncthreads();   // all waves done reading tile t
            writeLDS();        // vmcnt wait lands here, hidden by compute above
            __syncthreads();
        }
    }

    // epilogue: v = relu(h + b1p); p[j] = sum_h v * W2[h][j]; reduce over 16 lanes
    float b1v[4], w2v[4][KK];
#pragma unroll
    for (int nt = 0; nt < 4; ++nt) {
        int h = wn * 64 + nt * 16 + (lane & 15);
        b1v[nt] = b1p[h];
#pragma unroll
        for (int j = 0; j < KK; ++j) w2v[nt][j] = W2[h * KK + j];
    }
#pragma unroll
    for (int mt = 0; mt < 2; ++mt) {
        float p[4][KK];
#pragma unroll
        for (int r = 0; r < 4; ++r)
#pragma unroll
            for (int j = 0; j < KK; ++j) p[r][j] = 0.f;
#pragma unroll
        for (int nt = 0; nt < 4; ++nt)
#pragma unroll
            for (int r = 0; r < 4; ++r) {
                float v = fmaxf(acc[mt][nt][r] + b1v[nt], 0.f);
#pragma unroll
                for (int j = 0; j < KK; ++j) p[r][j] = fmaf(v, w2v[nt][j], p[r][j]);
            }
#pragma unroll
        for (int off = 1; off < 16; off <<= 1)
#pragma unroll
            for (int r = 0; r < 4; ++r)
#pragma unroll
                for (int j = 0; j < KK; ++j) p[r][j] += __shfl_xor(p[r][j], off, 64);
        if ((lane & 15) == 0) {
            int rowbase = wm * 32 + mt * 16 + (lane >> 4) * 4;
#pragma unroll
            for (int r = 0; r < 4; ++r)
#pragma unroll
                for (int j = 0; j < KK; ++j) pbuf[rowbase + r][wn][j] = p[r][j];
        }
    }
    __syncthreads();
    if (tid < 64) {
        int node = nodeBase + tid;
        float a[KK], an2 = 0.f;
#pragma unroll
        for (int j = 0; j < KK; ++j) {
            a[j] = pbuf[tid][0][j] + pbuf[tid][1][j] + b2[j];
            an2 = fmaf(a[j], a[j], an2);
        }
        float an = sqrtf(an2);
        bool valid = (an2 > 0.f) && isfinite(an);
        if (node < NN) {
#pragma unroll
            for (int j = 0; j < KK; ++j)
                gout[j * NN + node] = valid ? (a[j] / an) : RSQRT5;
        }
    }
}

// ---------------- walk step 1: state is uniform INIT_VAL, no read ----------------
__global__ void walk_step_first(const float* __restrict__ g, const int* __restrict__ nbrT,
                                float* __restrict__ v) {
    int i = blockIdx.x * blockDim.x + threadIdx.x;
    if (i >= NN) return;
    float gj[KK], s = 0.f;
#pragma unroll
    for (int j = 0; j < KK; ++j) {
        gj[j] = g[j * NN + i];
        s += gj[j];
    }
    float d = s * INIT_VAL;
#pragma unroll
    for (int j = 0; j < KK; ++j)
        atomicAdd(&v[j * NN + nbrT[j * NN + i]], gj[j] * d);
}

// ---------------- walk step: s_p = g (g.u); scatter-add ----------------
__global__ void walk_step_kernel(const float* __restrict__ g, const int* __restrict__ nbrT,
                                 const float* __restrict__ u, float* __restrict__ v) {
    int i = blockIdx.x * blockDim.x + threadIdx.x;
    if (i >= NN) return;
    float gj[KK], d = 0.f;
#pragma unroll
    for (int j = 0; j < KK; ++j) {
        gj[j] = g[j * NN + i];
        d = fmaf(gj[j], u[j * NN + i], d);
    }
#pragma unroll
    for (int j = 0; j < KK; ++j)
        atomicAdd(&v[j * NN + nbrT[j * NN + i]], gj[j] * d);
}

// ---------------- global sum of squares (float4) ----------------
__global__ void norm_reduce_kernel(const float* __restrict__ u, float* __restrict__ ss) {
    int i = blockIdx.x * blockDim.x + threadIdx.x;
    const int total4 = (KK * NN) / 4;  // 125000
    float s = 0.f;
    for (int idx = i; idx < total4; idx += gridDim.x * blockDim.x) {
        float4 x = reinterpret_cast<const float4*>(u)[idx];
        s = fmaf(x.x, x.x, s);
        s = fmaf(x.y, x.y, s);
        s = fmaf(x.z, x.z, s);
        s = fmaf(x.w, x.w, s);
    }
#pragma unroll
    for (int off = 32; off > 0; off >>= 1) s += __shfl_xor(s, off, 64);
    if ((threadIdx.x & 63) == 0) atomicAdd(ss, s);
}

// ---------------- out[i] = sum_j |u[j][i]| / ||u|| ----------------
__global__ void finalize_kernel(const float* __restrict__ u, const float* __restrict__ ss,
                                float* __restrict__ out) {
    int i = blockIdx.x * blockDim.x + threadIdx.x;
    if (i >= NN) return;
    float s = 0.f;
#pragma unroll
    for (int j = 0; j < KK; ++j) s += fabsf(u[j * NN + i]);
    float nrm = sqrtf(*ss);
    out[i] = (nrm > 0.f) ? (s / nrm) : (KK * INIT_VAL);
}

extern "C" void kernel_launch(void* const* d_in, const int* in_sizes, int n_in,
                              void* d_out, int out_size, void* d_ws, size_t ws_size,
                              hipStream_t stream) {
    const float* emb = (const float*)d_in[0];
    const float* qv  = (const float*)d_in[1];
    const float* W1  = (const float*)d_in[2];
    const float* b1  = (const float*)d_in[3];
    const float* W2  = (const float*)d_in[4];
    const float* b2  = (const float*)d_in[5];
    const int*   nbr = (const int*)d_in[6];
    float* out = (float*)d_out;

    char* ws = (char*)d_ws;
    size_t off = 0;
    auto alloc = [&](size_t bytes) {
        char* p = ws + off;
        off += (bytes + 255) & ~(size_t)255;
        return p;
    };
    float*  b1p  = (float*)alloc(HH * sizeof(float));
    ushort* W1h  = (ushort*)alloc((size_t)DD * HH * sizeof(ushort));
    ushort* W1l  = (ushort*)alloc((size_t)DD * HH * sizeof(ushort));
    float*  gbuf = (float*)alloc((size_t)KK * NN * sizeof(float));
    int*    nbrT = (int*)  alloc((size_t)KK * NN * sizeof(int));
    float*  sA   = (float*)alloc((size_t)KK * NN * sizeof(float));
    float*  sB   = (float*)alloc((size_t)KK * NN * sizeof(float));
    float*  sC   = (float*)alloc((size_t)KK * NN * sizeof(float));
    float*  ssp  = (float*)alloc(sizeof(float));

    const int nblk = (NN + 255) / 256;

    prep_kernel<<<25 + nblk, 256, 0, stream>>>(qv, W1, b1, nbr, b1p, W1h, W1l,
                                               nbrT, sA, sB, sC, ssp);
    mlp_mfma_kernel<<<(NN + 63) / 64, 256, 0, stream>>>(emb, W1h, W1l, b1p, W2, b2, gbuf);

    walk_step_first<<<nblk, 256, 0, stream>>>(gbuf, nbrT, sA);
    walk_step_kernel<<<nblk, 256, 0, stream>>>(gbuf, nbrT, sA, sB);
    walk_step_kernel<<<nblk, 256, 0, stream>>>(gbuf, nbrT, sB, sC);

    norm_reduce_kernel<<<512, 256, 0, stream>>>(sC, ssp);
    finalize_kernel<<<nblk, 256, 0, stream>>>(sC, ssp, out);
}